// Round 12
// baseline (2819.734 us; speedup 1.0000x reference)
//
#include <hip/hip_runtime.h>

#define DEVINL __device__ __forceinline__

typedef unsigned short u16;
typedef short bf16x8 __attribute__((ext_vector_type(8)));
typedef float f32x4 __attribute__((ext_vector_type(4)));
typedef unsigned short u16x4 __attribute__((ext_vector_type(4)));

DEVINL float lrelu(float v) { return v >= 0.f ? v : 0.01f * v; }

DEVINL u16 f2bf(float f) {
    unsigned u = __builtin_bit_cast(unsigned, f);
    unsigned r = (u + 0x7fffu + ((u >> 16) & 1u)) >> 16;
    return (u16)r;
}
DEVINL float bfhi(u16 h) {
    unsigned u = ((unsigned)h) << 16;
    return __builtin_bit_cast(float, u);
}

// ---------------------------------------------------------------------------
// Repack conv weights [COUT][CIN][K] -> wq[cb][k][iq][og][o16*4+ii]
// ---------------------------------------------------------------------------
template<int CIN, int COUT, int K>
__global__ __launch_bounds__(256) void repack_w(const float* __restrict__ w,
                                                float* __restrict__ wq)
{
    int f = blockIdx.x * 256 + threadIdx.x;
    if (f >= CIN * COUT * K) return;
    constexpr int NOG = COUT / 16;
    int ii   = f & 3;
    int o16  = (f >> 2) & 15;
    int rest = f >> 6;
    int og   = rest % NOG;
    int r2   = rest / NOG;
    int iq   = r2 & 3;
    int r3   = r2 >> 2;
    int k    = r3 % K;
    int cb   = r3 / K;
    int o = og * 16 + o16;
    int i = cb * 16 + iq * 4 + ii;
    wq[f] = w[((size_t)o * CIN + i) * K + k];
}

// ---------------------------------------------------------------------------
// conv_dnn8<NT>: r3-proven conv_dnn5 body at NT threads (NT/64 waves/block).
// Each wave owns ONE og-group with the unchanged acc[16][2] (VGPR ~48 —
// r6/r8 proved register growth past 64 regresses). Block's x-tile staging is
// shared by NT/64 og-groups; per-output fmaf chain (cb asc, k asc, iq asc,
// ii asc) IDENTICAL -> q_in bit-exact (FROZEN; VQ near-ties, r4/r5).
// NT=512 (r11-proven) for h3/h4 (keeps 2 blocks/CU overlap);
// NT=1024 for h2 only (512 blocks = still 2/CU, staging redundancy 1x).
// ---------------------------------------------------------------------------
template<int CIN, int COUT, int K, int S, int P, bool ACT, int LIN, int LOUT, int NT>
__global__ __launch_bounds__(NT) void conv_dnn8(const float* __restrict__ x,
                                                const float* __restrict__ wq,
                                                const float* __restrict__ bias,
                                                float* __restrict__ y)
{
    constexpr int T_TILE = 128;
    constexpr int NA   = 2;
    constexpr int SPAN = (T_TILE - 1) * S + K;
    constexpr int PH   = (S == 2) ? (SPAN / 2 + 1) : SPAN;
    constexpr int RS   = 20;
    constexpr int NPAR = (S == 2) ? 2 : 1;
    constexpr int NOG  = COUT / 16;
    constexpr int NW   = NT / 64;

    __shared__ float xsT[NPAR][PH][RS];

    const int tid  = threadIdx.x;
    const int lane = tid & 63;
    const int wid  = __builtin_amdgcn_readfirstlane(tid >> 6);   // 0..NW-1
    const int t0   = blockIdx.x * T_TILE;
    const int ogg  = blockIdx.y * NW + wid;
    const int b    = blockIdx.z;
    const int x0   = t0 * S - P;

    float acc[16][NA];
#pragma unroll
    for (int o16 = 0; o16 < 16; ++o16)
#pragma unroll
        for (int a = 0; a < NA; ++a) acc[o16][a] = 0.f;

    const float* xb = x + (size_t)b * CIN * LIN;

    for (int cb = 0; cb < CIN / 16; ++cb) {
        if (cb) __syncthreads();
        for (int idx = tid; idx < 16 * SPAN; idx += NT) {
            int i = idx / SPAN, s = idx - i * SPAN;
            int g = x0 + s;
            float v = (g >= 0 && g < LIN) ? xb[(size_t)(cb * 16 + i) * LIN + g] : 0.f;
            int u   = (S == 2) ? (s >> 1) : s;
            int par = (S == 2) ? (s & 1) : 0;
            int c = (((i >> 2) ^ ((u >> 3) & 3)) << 2) | (i & 3);
            xsT[par][u][c] = v;
        }
        __syncthreads();

#pragma unroll
        for (int k = 0; k < K; ++k) {
#pragma unroll
            for (int iq = 0; iq < 4; ++iq) {
                float xq[NA][4];
#pragma unroll
                for (int a = 0; a < NA; ++a) {
                    int s = (lane + 64 * a) * S + k;
                    int u   = (S == 2) ? (s >> 1) : s;
                    int par = (S == 2) ? (s & 1) : 0;
                    int col = ((iq ^ ((u >> 3) & 3)) << 2);
                    float4 t = *(const float4*)&xsT[par][u][col];
                    xq[a][0] = t.x; xq[a][1] = t.y; xq[a][2] = t.z; xq[a][3] = t.w;
                }
                const float* wp = wq + ((((size_t)cb * K + k) * 4 + iq) * NOG + ogg) * 64;
#pragma unroll
                for (int o16 = 0; o16 < 16; ++o16) {
                    float4 wv = *(const float4*)&wp[o16 * 4];
#pragma unroll
                    for (int a = 0; a < NA; ++a) {
                        acc[o16][a] = fmaf(xq[a][0], wv.x, acc[o16][a]);
                        acc[o16][a] = fmaf(xq[a][1], wv.y, acc[o16][a]);
                        acc[o16][a] = fmaf(xq[a][2], wv.z, acc[o16][a]);
                        acc[o16][a] = fmaf(xq[a][3], wv.w, acc[o16][a]);
                    }
                }
            }
        }
    }

#pragma unroll
    for (int o16 = 0; o16 < 16; ++o16) {
        const int o = ogg * 16 + o16;
        const float bv = bias[o];
#pragma unroll
        for (int a = 0; a < NA; ++a) {
            float r = acc[o16][a] + bv;
            if (ACT) r = lrelu(r);
            y[((size_t)b * COUT + o) * LOUT + t0 + lane + 64 * a] = r;
        }
    }
}

// ---------------------------------------------------------------------------
// h5qin_fused (r10-proven): h5 (256->64,K=1) + q_in (64->64,K=1), one kernel.
// ---------------------------------------------------------------------------
__global__ __launch_bounds__(256) void h5qin_fused(const float* __restrict__ x,
                                                   const float* __restrict__ wq5,
                                                   const float* __restrict__ b5,
                                                   const float* __restrict__ wqq,
                                                   const float* __restrict__ qb,
                                                   float* __restrict__ qin)
{
    constexpr int RS = 20;
    __shared__ float xsT[128][RS];
    __shared__ float mid[4][128][RS];

    const int tid  = threadIdx.x;
    const int lane = tid & 63;
    const int wid  = __builtin_amdgcn_readfirstlane(tid >> 6);
    const int t0   = blockIdx.x * 128;
    const int b    = blockIdx.z;

    const float* xb = x + (size_t)b * 256 * 1024;

    float acc[16][2];
#pragma unroll
    for (int o16 = 0; o16 < 16; ++o16) { acc[o16][0] = 0.f; acc[o16][1] = 0.f; }

    for (int cb = 0; cb < 16; ++cb) {
        if (cb) __syncthreads();
        for (int idx = tid; idx < 16 * 128; idx += 256) {
            int i = idx >> 7, s = idx & 127;
            int g = t0 + s;
            float v = (g >= 0 && g < 1024) ? xb[(size_t)(cb * 16 + i) * 1024 + g] : 0.f;
            int c = (((i >> 2) ^ ((s >> 3) & 3)) << 2) | (i & 3);
            xsT[s][c] = v;
        }
        __syncthreads();

#pragma unroll
        for (int iq = 0; iq < 4; ++iq) {
            float xq[2][4];
#pragma unroll
            for (int a = 0; a < 2; ++a) {
                int u = lane + 64 * a;
                int col = ((iq ^ ((u >> 3) & 3)) << 2);
                float4 t = *(const float4*)&xsT[u][col];
                xq[a][0] = t.x; xq[a][1] = t.y; xq[a][2] = t.z; xq[a][3] = t.w;
            }
            const float* wp = wq5 + (((size_t)cb * 4 + iq) * 4 + wid) * 64;
#pragma unroll
            for (int o16 = 0; o16 < 16; ++o16) {
                float4 wv = *(const float4*)&wp[o16 * 4];
#pragma unroll
                for (int a = 0; a < 2; ++a) {
                    acc[o16][a] = fmaf(xq[a][0], wv.x, acc[o16][a]);
                    acc[o16][a] = fmaf(xq[a][1], wv.y, acc[o16][a]);
                    acc[o16][a] = fmaf(xq[a][2], wv.z, acc[o16][a]);
                    acc[o16][a] = fmaf(xq[a][3], wv.w, acc[o16][a]);
                }
            }
        }
    }

    __syncthreads();
#pragma unroll
    for (int o16 = 0; o16 < 16; ++o16) {
        const int o = wid * 16 + o16;
        const float bv = b5[o];
#pragma unroll
        for (int a = 0; a < 2; ++a) {
            float r = lrelu(acc[o16][a] + bv);
            int u = lane + 64 * a;
            int c = (((o16 >> 2) ^ ((u >> 3) & 3)) << 2) | (o16 & 3);
            mid[wid][u][c] = r;
        }
    }
    __syncthreads();

    float acc2[16][2];
#pragma unroll
    for (int o16 = 0; o16 < 16; ++o16) { acc2[o16][0] = 0.f; acc2[o16][1] = 0.f; }

#pragma unroll
    for (int cb2 = 0; cb2 < 4; ++cb2) {
#pragma unroll
        for (int iq = 0; iq < 4; ++iq) {
            float xq[2][4];
#pragma unroll
            for (int a = 0; a < 2; ++a) {
                int u = lane + 64 * a;
                int col = ((iq ^ ((u >> 3) & 3)) << 2);
                float4 t = *(const float4*)&mid[cb2][u][col];
                xq[a][0] = t.x; xq[a][1] = t.y; xq[a][2] = t.z; xq[a][3] = t.w;
            }
            const float* wp = wqq + (((size_t)cb2 * 4 + iq) * 4 + wid) * 64;
#pragma unroll
            for (int o16 = 0; o16 < 16; ++o16) {
                float4 wv = *(const float4*)&wp[o16 * 4];
#pragma unroll
                for (int a = 0; a < 2; ++a) {
                    acc2[o16][a] = fmaf(xq[a][0], wv.x, acc2[o16][a]);
                    acc2[o16][a] = fmaf(xq[a][1], wv.y, acc2[o16][a]);
                    acc2[o16][a] = fmaf(xq[a][2], wv.z, acc2[o16][a]);
                    acc2[o16][a] = fmaf(xq[a][3], wv.w, acc2[o16][a]);
                }
            }
        }
    }

#pragma unroll
    for (int o16 = 0; o16 < 16; ++o16) {
        const int o = wid * 16 + o16;
        const float bv = qb[o];
#pragma unroll
        for (int a = 0; a < 2; ++a)
            qin[((size_t)b * 64 + o) * 1024 + t0 + lane + 64 * a] = acc2[o16][a] + bv;
    }
}

// ---------------------------------------------------------------------------
// E1 oneDNN order (bit-exact, frozen).
// ---------------------------------------------------------------------------
__global__ __launch_bounds__(256) void e1_dnn(const float* __restrict__ x,
                                              const float* __restrict__ w1,
                                              const float* __restrict__ b1,
                                              float* __restrict__ y)
{
    const int tid = threadIdx.x;
    const int t0  = blockIdx.x * 1024 + tid * 4;
    const int o   = blockIdx.y;
    const int b   = blockIdx.z;

    float wr[2][4];
#pragma unroll
    for (int i = 0; i < 2; ++i)
#pragma unroll
        for (int k = 0; k < 4; ++k) wr[i][k] = w1[(o * 2 + i) * 4 + k];
    const float bv = b1[o];

    float acc[4] = {0.f, 0.f, 0.f, 0.f};
#pragma unroll
    for (int k = 0; k < 4; ++k)
#pragma unroll
        for (int i = 0; i < 2; ++i) {
            const float* xb = x + ((size_t)b * 2 + i) * 8192;
#pragma unroll
            for (int a = 0; a < 4; ++a) {
                int p = (t0 + a) * 2 - 1 + k;
                float v = (p >= 0 && p < 8192) ? xb[p] : 0.f;
                acc[a] = fmaf(v, wr[i][k], acc[a]);
            }
        }
    float4 r;
    r.x = lrelu(acc[0] + bv); r.y = lrelu(acc[1] + bv);
    r.z = lrelu(acc[2] + bv); r.w = lrelu(acc[3] + bv);
    *(float4*)&y[((size_t)b * 128 + o) * 4096 + t0] = r;
}

// ---------------------------------------------------------------------------
// Codebook prep + VQ (vq_exact2: r8-r11-proven).
// ---------------------------------------------------------------------------
__global__ void cbt_kernel(const float* __restrict__ cb, float* __restrict__ cbT)
{
    int idx = blockIdx.x * 256 + threadIdx.x;
    if (idx < 512 * 64) {
        int k = idx >> 6, d = idx & 63;
        cbT[d * 512 + k] = cb[idx];
    }
}

__global__ void norms_kernel(const float* __restrict__ cb, float* __restrict__ norms)
{
#pragma clang fp contract(off)
    int k = blockIdx.x * 256 + threadIdx.x;
    if (k < 512) {
        float s = 0.f;
        for (int d = 0; d < 64; ++d) {
            float c = cb[k * 64 + d];
            float sq = c * c;
            s = s + sq;
        }
        norms[k] = s;
    }
}

__global__ __launch_bounds__(256) void vq_exact2(const float* __restrict__ qin,
                                                 const float* __restrict__ cb,
                                                 const float* __restrict__ cbT,
                                                 const float* __restrict__ norms,
                                                 float* __restrict__ st,
                                                 double* __restrict__ lacc)
{
#pragma clang fp contract(off)
    __shared__ double wsum[8];
    const int tid  = threadIdx.x;
    const int lane = tid & 63;
    const int wv   = tid >> 6;
    const size_t n0 = (size_t)blockIdx.x * 8 + wv * 2;

    const float qv0 = qin[n0 * 64 + lane];
    const float qv1 = qin[(n0 + 1) * 64 + lane];

    float A0 = 0.f, A1 = 0.f;
    for (int d = 0; d < 64; ++d) {
        float q0 = __shfl(qv0, d);
        float s0 = q0 * q0;
        A0 = A0 + s0;
        float q1 = __shfl(qv1, d);
        float s1 = q1 * q1;
        A1 = A1 + s1;
    }

    float AB0[8] = {0.f,0.f,0.f,0.f,0.f,0.f,0.f,0.f};
    float AB1[8] = {0.f,0.f,0.f,0.f,0.f,0.f,0.f,0.f};
    for (int d = 0; d < 64; ++d) {
        float q0 = __shfl(qv0, d);
        float q1 = __shfl(qv1, d);
#pragma unroll
        for (int r = 0; r < 8; ++r) {
            float c = cbT[d * 512 + r * 64 + lane];
            AB0[r] = fmaf(q0, c, AB0[r]);
            AB1[r] = fmaf(q1, c, AB1[r]);
        }
    }

    double parts[2];
#pragma unroll
    for (int j = 0; j < 2; ++j) {
        const float qv = j ? qv1 : qv0;
        const float A  = j ? A1 : A0;
        const float* AB = j ? AB1 : AB0;
        const size_t n = n0 + j;

        float bd = 1e30f;
        int   bk = 0x7fffffff;
#pragma unroll
        for (int r = 0; r < 8; ++r) {
            int k = r * 64 + lane;
            float t1 = A + norms[k];
            float c2 = 2.f * AB[r];
            float dk = t1 - c2;
            if (dk < bd) { bd = dk; bk = k; }
        }
#pragma unroll
        for (int off = 32; off > 0; off >>= 1) {
            float od = __shfl_down(bd, off);
            int   ok = __shfl_down(bk, off);
            if (od < bd || (od == bd && ok < bk)) { bd = od; bk = ok; }
        }
        const int kb = __shfl(bk, 0);

        const float c   = cb[(size_t)kb * 64 + lane];
        const float dif = c - qv;
        const float stv = qv + dif;
        st[n * 64 + lane] = stv;
        float sq = dif * dif;
        double part = (double)sq;
#pragma unroll
        for (int off = 32; off > 0; off >>= 1) part += __shfl_down(part, off);
        parts[j] = part;
    }
    if (lane == 0) { wsum[wv * 2] = parts[0]; wsum[wv * 2 + 1] = parts[1]; }
    __syncthreads();
    if (tid == 0)
        atomicAdd(lacc, ((wsum[0] + wsum[1]) + (wsum[2] + wsum[3]))
                      + ((wsum[4] + wsum[5]) + (wsum[6] + wsum[7])));
}

__global__ void zero_kernel(double* __restrict__ p) { p[0] = 0.0; }

__global__ void finalize_kernel(const double* __restrict__ acc, float* __restrict__ out)
{
    out[0] = (float)(1.25 * (acc[0] / 4194304.0));
}

// ---------------------------------------------------------------------------
// fp32 conv (decoder g1). OSPLIT=true: epilogue emits bf16 hi/lo [B][L][C].
// ---------------------------------------------------------------------------
template<int CIN, int COUT, int K, int STRIDE, int PAD, bool ACT, int LIN, int LOUT, int CI_CHUNK, int WT, bool OSPLIT>
__global__ __launch_bounds__(256) void conv_kernel(const float* __restrict__ x,
                                                   const float* __restrict__ w,
                                                   const float* __restrict__ bias,
                                                   float* __restrict__ y,
                                                   u16* __restrict__ yhi,
                                                   u16* __restrict__ ylo)
{
    constexpr int SPAN  = 127 * STRIDE + K;
    constexpr int SPANP = ((SPAN + 11) & ~3);
    constexpr int NEED  = 3 * STRIDE + K;
    constexpr int NV    = (NEED + 3) / 4;
    constexpr int KP    = (K >= 3) ? 4 : K;

    __shared__ float xs[CI_CHUNK][SPANP];
    __shared__ float ws[32][CI_CHUNK][KP];

    const int tid = threadIdx.x;
    const int tt  = tid & 31;
    const int tg  = tid >> 5;
    const int t0  = blockIdx.x * 128;
    const int ob  = blockIdx.y * 32;
    const int b   = blockIdx.z;

    float acc[4][4];
#pragma unroll
    for (int j = 0; j < 4; ++j) { acc[j][0]=0.f; acc[j][1]=0.f; acc[j][2]=0.f; acc[j][3]=0.f; }

    const float* xb = x + (size_t)b * CIN * LIN;
    const int x0 = t0 * STRIDE - PAD;

    for (int ci = 0; ci < CIN; ci += CI_CHUNK) {
        for (int idx = tid; idx < CI_CHUNK * SPAN; idx += 256) {
            int i = idx / SPAN, s = idx - i * SPAN;
            int tin = x0 + s;
            xs[i][s] = (tin >= 0 && tin < LIN) ? xb[(size_t)(ci + i) * LIN + tin] : 0.f;
        }
        for (int idx = tid; idx < 32 * CI_CHUNK * K; idx += 256) {
            int o = idx / (CI_CHUNK * K);
            int rem = idx - o * (CI_CHUNK * K);
            int i = rem / K, k = rem - i * K;
            if constexpr (WT == 0)
                ws[o][i][k] = w[((size_t)(ob + o) * CIN + (ci + i)) * K + k];
            else
                ws[o][i][k] = w[((size_t)(ci + i) * COUT + (ob + o)) * K + (K - 1 - k)];
        }
        __syncthreads();

#pragma unroll 4
        for (int i = 0; i < CI_CHUNK; ++i) {
            float xv[NV * 4];
#pragma unroll
            for (int v = 0; v < NV; ++v) {
                float4 t = *(const float4*)&xs[i][tt * 4 * STRIDE + 4 * v];
                xv[4*v+0]=t.x; xv[4*v+1]=t.y; xv[4*v+2]=t.z; xv[4*v+3]=t.w;
            }
#pragma unroll
            for (int j = 0; j < 4; ++j) {
                float wv[KP];
                if constexpr (KP == 4) {
                    float4 t = *(const float4*)&ws[tg*4+j][i][0];
                    wv[0]=t.x; wv[1]=t.y; wv[2]=t.z; wv[3]=t.w;
                } else {
                    wv[0] = ws[tg*4+j][i][0];
                    if constexpr (KP >= 2) wv[1] = ws[tg*4+j][i][1];
                }
#pragma unroll
                for (int a = 0; a < 4; ++a)
#pragma unroll
                    for (int k = 0; k < K; ++k)
                        acc[j][a] += xv[a * STRIDE + k] * wv[k];
            }
        }
        __syncthreads();
    }

    if constexpr (OSPLIT) {
        float rv[4][4];
#pragma unroll
        for (int j = 0; j < 4; ++j) {
            const float bv = bias[ob + tg * 4 + j];
#pragma unroll
            for (int a = 0; a < 4; ++a) {
                float r = acc[j][a] + bv;
                rv[j][a] = ACT ? lrelu(r) : r;
            }
        }
#pragma unroll
        for (int a = 0; a < 4; ++a) {
            u16x4 hv, lv;
#pragma unroll
            for (int j = 0; j < 4; ++j) {
                u16 h = f2bf(rv[j][a]);
                hv[j] = h;
                lv[j] = f2bf(rv[j][a] - bfhi(h));
            }
            const int t = t0 + 4 * tt + a;
            size_t oa = ((size_t)b * LOUT + t) * COUT + ob + tg * 4;
            *(u16x4*)&yhi[oa] = hv;
            *(u16x4*)&ylo[oa] = lv;
        }
    } else {
#pragma unroll
        for (int j = 0; j < 4; ++j) {
            const int o = ob + tg * 4 + j;
            const float bv = bias[o];
            float4 r;
            r.x = acc[j][0] + bv; r.y = acc[j][1] + bv; r.z = acc[j][2] + bv; r.w = acc[j][3] + bv;
            if constexpr (ACT) { r.x=lrelu(r.x); r.y=lrelu(r.y); r.z=lrelu(r.z); r.w=lrelu(r.w); }
            *(float4*)&y[((size_t)b * COUT + o) * LOUT + t0 + 4 * tt] = r;
        }
    }
}

// ---------------------------------------------------------------------------
// Repack ConvT1d weights [CIN][COUT][4] into per-lane MFMA A-fragments (hi/lo).
// ---------------------------------------------------------------------------
template<int CIN, int COUT>
__global__ __launch_bounds__(256) void repack_wt_mfma(const float* __restrict__ w,
                                                      u16* __restrict__ wf)
{
    constexpr int NKC = CIN / 32, NOG = COUT / 16;
    int idx = blockIdx.x * 256 + threadIdx.x;
    if (idx >= NKC * NOG * 4 * 2 * 512) return;
    int e    = idx & 7;
    int lane = (idx >> 3) & 63;
    int h    = (idx >> 9) & 1;
    int pt   = (idx >> 10) & 3;
    int rest = idx >> 12;
    int og = rest & (NOG - 1);
    int kc = rest / NOG;
    int i = kc * 32 + (lane >> 4) * 8 + e;
    int o = og * 16 + (lane & 15);
    int k = (pt == 0) ? 1 : (pt == 1) ? 3 : (pt == 2) ? 0 : 2;
    float f = w[((size_t)i * COUT + o) * 4 + k];
    u16 hb = f2bf(f);
    u16 v  = h ? f2bf(f - bfhi(hb)) : hb;
    wf[idx] = v;
}

// ---------------------------------------------------------------------------
// Repack conv-like weights -> double-split MFMA fragments (decoder g2).
// ---------------------------------------------------------------------------
template<int CIN, int COUT, int K, int WT>
__global__ __launch_bounds__(256) void repack_wc_mfma(const float* __restrict__ w,
                                                      u16* __restrict__ wf)
{
    constexpr int NKC = CIN / 32, NOG = COUT / 16;
    int idx = blockIdx.x * 256 + threadIdx.x;
    if (idx >= NKC * NOG * K * 2 * 512) return;
    int e    = idx & 7;
    int lane = (idx >> 3) & 63;
    int h    = (idx >> 9) & 1;
    int rem  = idx >> 10;
    int kt   = rem % K;
    int rest = rem / K;
    int og = rest % NOG;
    int kc = rest / NOG;
    int i = kc * 32 + (lane >> 4) * 8 + e;
    int o = og * 16 + (lane & 15);
    float f;
    if constexpr (WT == 0)
        f = w[((size_t)o * CIN + i) * K + kt];
    else
        f = w[((size_t)i * COUT + o) * K + (K - 1 - kt)];
    u16 hb = f2bf(f);
    u16 v  = h ? f2bf(f - bfhi(hb)) : hb;
    wf[idx] = v;
}

#define MFMA_B16(a,b,c) __builtin_amdgcn_mfma_f32_16x16x32_bf16((a),(b),(c),0,0,0)
#define LDSB(arr,row,slot) (*(const bf16x8*)&(arr)[(((row)*16 + ((slot) ^ ((row)&7)))*8)])

// ---------------------------------------------------------------------------
// MFMA Conv1d K=3 S=1 P=1 via double split-bf16 (decoder g2).
// launch_bounds (256,4): LDS 33.8KB*4=135KB <= 160KB, VGPR cap 128 >= 100 —
// occupancy 2 -> 4 blocks/CU; identical instruction stream (no numeric change).
// ---------------------------------------------------------------------------
template<int CIN, int COUT, int LIN>
__global__ __launch_bounds__(256, 4) void conv3_mfma(const u16* __restrict__ xhi,
                                                     const u16* __restrict__ xlo,
                                                     const u16* __restrict__ wf,
                                                     const float* __restrict__ bias,
                                                     u16* __restrict__ yhi,
                                                     u16* __restrict__ ylo)
{
    constexpr int NOG = COUT / 16;

    __shared__ __attribute__((aligned(16))) u16 lhi[66 * 128];
    __shared__ __attribute__((aligned(16))) u16 llo[66 * 128];

    const int tid  = threadIdx.x;
    const int lane = tid & 63;
    const int wid  = tid >> 6;
    const int n    = lane & 15;
    const int g    = lane >> 4;
    const int u0   = blockIdx.x * 64;
    const int ogp  = blockIdx.y * 4 + wid;
    const int og0  = ogp * 2;
    const int b    = blockIdx.z;

    f32x4 acc[2][4];
#pragma unroll
    for (int og = 0; og < 2; ++og)
#pragma unroll
        for (int us = 0; us < 4; ++us) {
            f32x4 z = {0.f, 0.f, 0.f, 0.f};
            acc[og][us] = z;
        }

    for (int ch = 0; ch < CIN; ch += 128) {
        if (ch) __syncthreads();
        for (int idx = tid; idx < 1056; idx += 256) {
            int row = idx >> 4, slot = idx & 15;
            int u = u0 - 1 + row;
            uint4 vh = {0u,0u,0u,0u}, vl = {0u,0u,0u,0u};
            if (u >= 0 && u < LIN) {
                size_t ga = ((size_t)b * LIN + u) * CIN + ch + slot * 8;
                vh = *(const uint4*)&xhi[ga];
                vl = *(const uint4*)&xlo[ga];
            }
            int sl = slot ^ (row & 7);
            *(uint4*)&lhi[(row * 16 + sl) * 8] = vh;
            *(uint4*)&llo[(row * 16 + sl) * 8] = vl;
        }
        __syncthreads();

#pragma unroll
        for (int kc = 0; kc < 4; ++kc) {
            const int kcg = (ch >> 5) + kc;
            const u16* wb = wf + ((size_t)(kcg * NOG + og0) * 3) * 1024 + lane * 8;
            bf16x8 A[2][3][2];
#pragma unroll
            for (int og = 0; og < 2; ++og)
#pragma unroll
                for (int kt = 0; kt < 3; ++kt)
#pragma unroll
                    for (int h = 0; h < 2; ++h)
                        A[og][kt][h] = *(const bf16x8*)(wb + (size_t)((og * 3 + kt) * 2 + h) * 512);

            const int slot = kc * 4 + g;
#pragma unroll
            for (int us = 0; us < 4; ++us) {
                const int r0 = us * 16 + n;
                bf16x8 Bh[3], Bl[3];
#pragma unroll
                for (int k = 0; k < 3; ++k) {
                    Bh[k] = LDSB(lhi, r0 + k, slot);
                    Bl[k] = LDSB(llo, r0 + k, slot);
                }
#pragma unroll
                for (int og = 0; og < 2; ++og) {
                    f32x4 a = acc[og][us];
#pragma unroll
                    for (int k = 0; k < 3; ++k) {
                        a = MFMA_B16(A[og][k][0], Bh[k], a);
                        a = MFMA_B16(A[og][k][0], Bl[k], a);
                        a = MFMA_B16(A[og][k][1], Bh[k], a);
                    }
                    acc[og][us] = a;
                }
            }
        }
    }

#pragma unroll
    for (int og = 0; og < 2; ++og) {
        const int ob = (og0 + og) * 16 + g * 4;
        const float4 bq = *(const float4*)&bias[ob];
        const float bvr[4] = {bq.x, bq.y, bq.z, bq.w};
#pragma unroll
        for (int us = 0; us < 4; ++us) {
            const int t = u0 + us * 16 + n;
            u16x4 hv, lv;
#pragma unroll
            for (int r = 0; r < 4; ++r) {
                float v = lrelu(acc[og][us][r] + bvr[r]);
                u16 h = f2bf(v);
                hv[r] = h;
                lv[r] = f2bf(v - bfhi(h));
            }
            size_t oa = ((size_t)b * LIN + t) * COUT + ob;
            *(u16x4*)&yhi[oa] = hv;
            *(u16x4*)&ylo[oa] = lv;
        }
    }
}

// ---------------------------------------------------------------------------
// MFMA ConvTranspose1d (K=4, S=2, P=1) via double split-bf16 (decoder g3/g4).
// launch_bounds (256,4): occupancy 2 -> 4 blocks/CU (see conv3_mfma note).
// ---------------------------------------------------------------------------
template<int CIN, int COUT, int LIN, bool OSPLIT>
__global__ __launch_bounds__(256, 4) void convt_mfma(const u16* __restrict__ xhi,
                                                     const u16* __restrict__ xlo,
                                                     const u16* __restrict__ wf,
                                                     const float* __restrict__ bias,
                                                     float* __restrict__ y,
                                                     u16* __restrict__ yhi,
                                                     u16* __restrict__ ylo)
{
    constexpr int LOUT = 2 * LIN;
    constexpr int NOG  = COUT / 16;

    __shared__ __attribute__((aligned(16))) u16 lhi[66 * 128];
    __shared__ __attribute__((aligned(16))) u16 llo[66 * 128];

    const int tid  = threadIdx.x;
    const int lane = tid & 63;
    const int wid  = tid >> 6;
    const int n    = lane & 15;
    const int g    = lane >> 4;
    const int u0   = blockIdx.x * 64;
    const int ogp  = blockIdx.y * 4 + wid;
    const int og0  = ogp * 2;
    const int b    = blockIdx.z;

    f32x4 acc[2][4][2];
#pragma unroll
    for (int og = 0; og < 2; ++og)
#pragma unroll
        for (int us = 0; us < 4; ++us)
#pragma unroll
            for (int p = 0; p < 2; ++p) {
                f32x4 z = {0.f, 0.f, 0.f, 0.f};
                acc[og][us][p] = z;
            }

    for (int ch = 0; ch < CIN; ch += 128) {
        if (ch) __syncthreads();
        for (int idx = tid; idx < 1056; idx += 256) {
            int row = idx >> 4, slot = idx & 15;
            int u = u0 - 1 + row;
            uint4 vh = {0u,0u,0u,0u}, vl = {0u,0u,0u,0u};
            if (u >= 0 && u < LIN) {
                size_t ga = ((size_t)b * LIN + u) * CIN + ch + slot * 8;
                vh = *(const uint4*)&xhi[ga];
                vl = *(const uint4*)&xlo[ga];
            }
            int sl = slot ^ (row & 7);
            *(uint4*)&lhi[(row * 16 + sl) * 8] = vh;
            *(uint4*)&llo[(row * 16 + sl) * 8] = vl;
        }
        __syncthreads();

#pragma unroll
        for (int kc = 0; kc < 4; ++kc) {
            const int kcg = (ch >> 5) + kc;
            const u16* w0 = wf + ((size_t)kcg * NOG + og0) * 4096 + lane * 8;
            bf16x8 A[2][8];
#pragma unroll
            for (int q = 0; q < 8; ++q) A[0][q] = *(const bf16x8*)(w0 + q * 512);
#pragma unroll
            for (int q = 0; q < 8; ++q) A[1][q] = *(const bf16x8*)(w0 + (8 + q) * 512);

            const int slot = kc * 4 + g;
#pragma unroll
            for (int us = 0; us < 4; ++us) {
                const int r0 = us * 16 + n;
                bf16x8 Bm1h = LDSB(lhi, r0,     slot);
                bf16x8 Bm1l = LDSB(llo, r0,     slot);
                bf16x8 B0h  = LDSB(lhi, r0 + 1, slot);
                bf16x8 B0l  = LDSB(llo, r0 + 1, slot);
                bf16x8 Bp1h = LDSB(lhi, r0 + 2, slot);
                bf16x8 Bp1l = LDSB(llo, r0 + 2, slot);
#pragma unroll
                for (int og = 0; og < 2; ++og) {
                    f32x4 ae = acc[og][us][0];
                    f32x4 ao = acc[og][us][1];
                    ae = MFMA_B16(A[og][0], B0h,  ae);
                    ae = MFMA_B16(A[og][0], B0l,  ae);
                    ae = MFMA_B16(A[og][1], B0h,  ae);
                    ae = MFMA_B16(A[og][2], Bm1h, ae);
                    ae = MFMA_B16(A[og][2], Bm1l, ae);
                    ae = MFMA_B16(A[og][3], Bm1h, ae);
                    ao = MFMA_B16(A[og][4], Bp1h, ao);
                    ao = MFMA_B16(A[og][4], Bp1l, ao);
                    ao = MFMA_B16(A[og][5], Bp1h, ao);
                    ao = MFMA_B16(A[og][6], B0h,  ao);
                    ao = MFMA_B16(A[og][6], B0l,  ao);
                    ao = MFMA_B16(A[og][7], B0h,  ao);
                    acc[og][us][0] = ae;
                    acc[og][us][1] = ao;
                }
            }
        }
    }

#pragma unroll
    for (int og = 0; og < 2; ++og) {
        const int ob = (og0 + og) * 16 + g * 4;
        const float4 bq = *(const float4*)&bias[ob];
        const float bvr[4] = {bq.x, bq.y, bq.z, bq.w};
#pragma unroll
        for (int us = 0; us < 4; ++us) {
            const int U = u0 + us * 16 + n;
            if constexpr (OSPLIT) {
                u16x4 he, le, ho, lo_;
#pragma unroll
                for (int r = 0; r < 4; ++r) {
                    float ev = lrelu(acc[og][us][0][r] + bvr[r]);
                    float ov = lrelu(acc[og][us][1][r] + bvr[r]);
                    u16 hev = f2bf(ev); he[r] = hev; le[r]  = f2bf(ev - bfhi(hev));
                    u16 hov = f2bf(ov); ho[r] = hov; lo_[r] = f2bf(ov - bfhi(hov));
                }
                size_t oe = ((size_t)b * LOUT + 2 * U) * COUT + ob;
                size_t oo = ((size_t)b * LOUT + 2 * U + 1) * COUT + ob;
                *(u16x4*)&yhi[oe] = he;
                *(u16x4*)&ylo[oe] = le;
                *(u16x4*)&yhi[oo] = ho;
                *(u16x4*)&ylo[oo] = lo_;
            } else {
#pragma unroll
                for (int r = 0; r < 4; ++r) {
                    float ev = acc[og][us][0][r] + bvr[r];
                    float ov = acc[og][us][1][r] + bvr[r];
                    float2 f2;
                    f2.x = lrelu(ev);
                    f2.y = lrelu(ov);
                    *(float2*)&y[((size_t)b * COUT + ob + r) * LOUT + 2 * U] = f2;
                }
            }
        }
    }
}

// ---------------------------------------------------------------------------
// d5b (r8-r11-proven): final convT 128->2, 128-thread blocks, u-tile 128.
// ---------------------------------------------------------------------------
__global__ __launch_bounds__(128) void d5b_kernel(const float* __restrict__ x,
                                                  const float* __restrict__ w,
                                                  const float* __restrict__ bias,
                                                  float* __restrict__ y)
{
    constexpr int CIN = 128, LIN = 4096, LOUT = 8192, CI_CHUNK = 16;
    constexpr int SPAN = 131, SPANP = 136;
    __shared__ float xs[CI_CHUNK][SPANP];
    __shared__ float wsm[2][CIN][4];
    __shared__ float bsm[2];

    const int tid = threadIdx.x;
    const int mb  = blockIdx.x * 128;
    const int b   = blockIdx.y;

    for (int idx = tid; idx < 1024; idx += 128) {
        int k = idx & 3, t = idx >> 2;
        int i = t & 127, o = t >> 7;
        wsm[o][i][k] = w[((size_t)i * 2 + o) * 4 + k];
    }
    if (tid < 2) bsm[tid] = bias[tid];

    float acc[2][2] = {{0.f, 0.f}, {0.f, 0.f}};
    const float* xb = x + (size_t)b * CIN * LIN;

    for (int ci = 0; ci < CIN; ci += CI_CHUNK) {
        for (int idx = tid; idx < CI_CHUNK * SPAN; idx += 128) {
            int i = idx / SPAN, s = idx - i * SPAN;
            int m = mb - 1 + s;
            xs[i][s] = (m >= 0 && m < LIN) ? xb[(size_t)(ci + i) * LIN + m] : 0.f;
        }
        __syncthreads();
#pragma unroll 4
        for (int i = 0; i < CI_CHUNK; ++i) {
            float a0 = xs[i][tid];
            float a1 = xs[i][tid + 1];
            float a2 = xs[i][tid + 2];
#pragma unroll
            for (int o = 0; o < 2; ++o) {
                float4 wv = *(const float4*)&wsm[o][ci + i][0];
                acc[o][0] += a1 * wv.y + a0 * wv.w;
                acc[o][1] += a2 * wv.x + a1 * wv.z;
            }
        }
        __syncthreads();
    }

    const int u = mb + tid;
#pragma unroll
    for (int o = 0; o < 2; ++o) {
        float2 r;
        r.x = acc[o][0] + bsm[o];
        r.y = acc[o][1] + bsm[o];
        *(float2*)&y[((size_t)b * 2 + o) * LOUT + 2 * u] = r;
    }
}

// ---------------------------------------------------------------------------
// Workspace layout = round 3 (proven):
//   A 0 | Bb 16777216 | C 33554432 | cbT 41943040 | norms 41975808
//   lacc 41976320 | wq2 41976336 | wq3 42107408 | wq4 42369552
//   wq5 42566160 | wqq 42582544 | wf3 42586640 | wf4 42848784 | wf2 42979856
// ---------------------------------------------------------------------------
extern "C" void kernel_launch(void* const* d_in, const int* in_sizes, int n_in,
                              void* d_out, int out_size, void* d_ws, size_t ws_size,
                              hipStream_t stream)
{
    const float* x   = (const float*)d_in[0];
    const float* w1  = (const float*)d_in[1];  const float* b1  = (const float*)d_in[2];
    const float* w2  = (const float*)d_in[3];  const float* b2  = (const float*)d_in[4];
    const float* w3  = (const float*)d_in[5];  const float* b3  = (const float*)d_in[6];
    const float* w4  = (const float*)d_in[7];  const float* b4  = (const float*)d_in[8];
    const float* w5  = (const float*)d_in[9];  const float* b5  = (const float*)d_in[10];
    const float* qw  = (const float*)d_in[11]; const float* qb  = (const float*)d_in[12];
    const float* cbk = (const float*)d_in[13];
    const float* dw1 = (const float*)d_in[14]; const float* db1 = (const float*)d_in[15];
    const float* dw2 = (const float*)d_in[16]; const float* db2 = (const float*)d_in[17];
    const float* dw3 = (const float*)d_in[18]; const float* db3 = (const float*)d_in[19];
    const float* dw4 = (const float*)d_in[20]; const float* db4 = (const float*)d_in[21];
    const float* dw5 = (const float*)d_in[22]; const float* db5 = (const float*)d_in[23];

    float* wsf   = (float*)d_ws;
    float* A     = wsf;
    float* Bb    = wsf + 16777216;
    float* C     = wsf + 33554432;
    float* cbT   = wsf + 41943040;
    float* norms = wsf + 41975808;
    double* lacc = (double*)(wsf + 41976320);
    float* wq2   = wsf + 41976336;
    float* wq3   = wsf + 42107408;
    float* wq4   = wsf + 42369552;
    float* wq5   = wsf + 42566160;
    float* wqq   = wsf + 42582544;
    u16*   wf3   = (u16*)(wsf + 42586640);
    u16*   wf4   = (u16*)(wsf + 42848784);
    u16*   wf2   = (u16*)(wsf + 42979856);

    float* h4  = A;
    float* qin = A + 10485760;
    float* st  = A + 12582912;

    cbt_kernel<<<128, 256, 0, stream>>>(cbk, cbT);
    norms_kernel<<<2, 256, 0, stream>>>(cbk, norms);
    zero_kernel<<<1, 1, 0, stream>>>(lacc);
    repack_w<128, 256, 4><<<512, 256, 0, stream>>>(w2, wq2);
    repack_w<256, 256, 4><<<1024, 256, 0, stream>>>(w3, wq3);
    repack_w<256, 256, 3><<<768, 256, 0, stream>>>(w4, wq4);
    repack_w<256, 64, 1><<<64, 256, 0, stream>>>(w5, wq5);
    repack_w<64, 64, 1><<<16, 256, 0, stream>>>(qw, wqq);
    repack_wc_mfma<256, 256, 3, 1><<<1536, 256, 0, stream>>>(dw2, wf2);
    repack_wt_mfma<256, 256><<<2048, 256, 0, stream>>>(dw3, wf3);
    repack_wt_mfma<256, 128><<<1024, 256, 0, stream>>>(dw4, wf4);

    constexpr int BS = 32;
    for (int s = 0; s < 2; ++s) {
        const float* xs   = x + (size_t)s * BS * 2 * 8192;
        float*       decs = (float*)d_out + (size_t)s * BS * 2 * 8192;

        // ---- encoder: bit-exact chains; h2 @16 waves, h3/h4 @8 waves ----
        e1_dnn<<<dim3(4, 128, BS), 256, 0, stream>>>(xs, w1, b1, A);                                  // h1
        conv_dnn8<128,256,4,2,1,true,4096,2048,1024><<<dim3(16,1,BS),1024,0,stream>>>(A, wq2, b2, Bb);// h2
        conv_dnn8<256,256,4,2,1,true,2048,1024,512><<<dim3(8,2,BS),512,0,stream>>>(Bb, wq3, b3, C);   // h3
        conv_dnn8<256,256,3,1,1,true,1024,1024,512><<<dim3(8,2,BS),512,0,stream>>>(C,  wq4, b4, h4);  // h4
        h5qin_fused<<<dim3(8, 1, BS), 256, 0, stream>>>(h4, wq5, b5, wqq, qb, qin);                   // h5 + q_in

        // ---- fp32 VQ (vq_exact2, r8-proven) ----
        vq_exact2<<<4096, 256, 0, stream>>>(qin, cbk, cbT, norms, st, lacc);

        // ---- decoder: g1 fp32 (split epilogue), g2/g3/g4 MFMA chain ----
        conv_kernel<64,256,1,1,0,true,1024,1024,32,1,true><<<dim3(8,8,BS),256,0,stream>>>(
            st, dw1, db1, nullptr, (u16*)C, (u16*)(C + 4194304));                                   // g1 -> hi/lo

        conv3_mfma<256,256,1024><<<dim3(16,2,BS),256,0,stream>>>(
            (const u16*)C, (const u16*)(C + 4194304), wf2, db2,
            (u16*)Bb, (u16*)(Bb + 4194304));                                                        // g2

        convt_mfma<256,256,1024,true><<<dim3(16,2,BS),256,0,stream>>>(
            (const u16*)Bb, (const u16*)(Bb + 4194304), wf3, db3,
            nullptr, (u16*)A, (u16*)(A + 8388608));                                                 // g3

        convt_mfma<256,128,2048,false><<<dim3(32,1,BS),256,0,stream>>>(
            (const u16*)A, (const u16*)(A + 8388608), wf4, db4,
            Bb, nullptr, nullptr);                                                                  // g4

        d5b_kernel<<<dim3(32, BS), 128, 0, stream>>>(Bb, dw5, db5, decs);                           // dec
    }

    finalize_kernel<<<1, 1, 0, stream>>>(lacc, (float*)d_out + 1048576);
}

// Round 13
// 2651.916 us; speedup vs baseline: 1.0633x; 1.0633x over previous
//
#include <hip/hip_runtime.h>

#define DEVINL __device__ __forceinline__

typedef unsigned short u16;
typedef short bf16x8 __attribute__((ext_vector_type(8)));
typedef float f32x4 __attribute__((ext_vector_type(4)));
typedef unsigned short u16x4 __attribute__((ext_vector_type(4)));

DEVINL float lrelu(float v) { return v >= 0.f ? v : 0.01f * v; }

DEVINL u16 f2bf(float f) {
    unsigned u = __builtin_bit_cast(unsigned, f);
    unsigned r = (u + 0x7fffu + ((u >> 16) & 1u)) >> 16;
    return (u16)r;
}
DEVINL float bfhi(u16 h) {
    unsigned u = ((unsigned)h) << 16;
    return __builtin_bit_cast(float, u);
}

// ---------------------------------------------------------------------------
// Repack conv weights [COUT][CIN][K] -> wq[cb][k][iq][og][o16*4+ii]
// ---------------------------------------------------------------------------
template<int CIN, int COUT, int K>
__global__ __launch_bounds__(256) void repack_w(const float* __restrict__ w,
                                                float* __restrict__ wq)
{
    int f = blockIdx.x * 256 + threadIdx.x;
    if (f >= CIN * COUT * K) return;
    constexpr int NOG = COUT / 16;
    int ii   = f & 3;
    int o16  = (f >> 2) & 15;
    int rest = f >> 6;
    int og   = rest % NOG;
    int r2   = rest / NOG;
    int iq   = r2 & 3;
    int r3   = r2 >> 2;
    int k    = r3 % K;
    int cb   = r3 / K;
    int o = og * 16 + o16;
    int i = cb * 16 + iq * 4 + ii;
    wq[f] = w[((size_t)o * CIN + i) * K + k];
}

// ---------------------------------------------------------------------------
// conv_dnn8: r11-proven — conv_dnn5 body at 512 threads / 8 waves per block.
// Each wave owns ONE og-group with acc[16][2] (VGPR 48; r6/r8: growth past
// the 64-VGPR cliff regresses). Block x-tile staging shared by 8 og-groups;
// per-output fmaf chain (cb asc, k asc, iq asc, ii asc) IDENTICAL ->
// q_in bit-exact (FROZEN; VQ near-ties, r4/r5). r12 measured 16-wave null.
// ---------------------------------------------------------------------------
template<int CIN, int COUT, int K, int S, int P, bool ACT, int LIN, int LOUT>
__global__ __launch_bounds__(512) void conv_dnn8(const float* __restrict__ x,
                                                 const float* __restrict__ wq,
                                                 const float* __restrict__ bias,
                                                 float* __restrict__ y)
{
    constexpr int T_TILE = 128;
    constexpr int NA   = 2;
    constexpr int SPAN = (T_TILE - 1) * S + K;
    constexpr int PH   = (S == 2) ? (SPAN / 2 + 1) : SPAN;
    constexpr int RS   = 20;
    constexpr int NPAR = (S == 2) ? 2 : 1;
    constexpr int NOG  = COUT / 16;

    __shared__ float xsT[NPAR][PH][RS];

    const int tid  = threadIdx.x;
    const int lane = tid & 63;
    const int wid  = __builtin_amdgcn_readfirstlane(tid >> 6);   // 0..7
    const int t0   = blockIdx.x * T_TILE;
    const int ogg  = blockIdx.y * 8 + wid;
    const int b    = blockIdx.z;
    const int x0   = t0 * S - P;

    float acc[16][NA];
#pragma unroll
    for (int o16 = 0; o16 < 16; ++o16)
#pragma unroll
        for (int a = 0; a < NA; ++a) acc[o16][a] = 0.f;

    const float* xb = x + (size_t)b * CIN * LIN;

    for (int cb = 0; cb < CIN / 16; ++cb) {
        if (cb) __syncthreads();
        for (int idx = tid; idx < 16 * SPAN; idx += 512) {
            int i = idx / SPAN, s = idx - i * SPAN;
            int g = x0 + s;
            float v = (g >= 0 && g < LIN) ? xb[(size_t)(cb * 16 + i) * LIN + g] : 0.f;
            int u   = (S == 2) ? (s >> 1) : s;
            int par = (S == 2) ? (s & 1) : 0;
            int c = (((i >> 2) ^ ((u >> 3) & 3)) << 2) | (i & 3);
            xsT[par][u][c] = v;
        }
        __syncthreads();

#pragma unroll
        for (int k = 0; k < K; ++k) {
#pragma unroll
            for (int iq = 0; iq < 4; ++iq) {
                float xq[NA][4];
#pragma unroll
                for (int a = 0; a < NA; ++a) {
                    int s = (lane + 64 * a) * S + k;
                    int u   = (S == 2) ? (s >> 1) : s;
                    int par = (S == 2) ? (s & 1) : 0;
                    int col = ((iq ^ ((u >> 3) & 3)) << 2);
                    float4 t = *(const float4*)&xsT[par][u][col];
                    xq[a][0] = t.x; xq[a][1] = t.y; xq[a][2] = t.z; xq[a][3] = t.w;
                }
                const float* wp = wq + ((((size_t)cb * K + k) * 4 + iq) * NOG + ogg) * 64;
#pragma unroll
                for (int o16 = 0; o16 < 16; ++o16) {
                    float4 wv = *(const float4*)&wp[o16 * 4];
#pragma unroll
                    for (int a = 0; a < NA; ++a) {
                        acc[o16][a] = fmaf(xq[a][0], wv.x, acc[o16][a]);
                        acc[o16][a] = fmaf(xq[a][1], wv.y, acc[o16][a]);
                        acc[o16][a] = fmaf(xq[a][2], wv.z, acc[o16][a]);
                        acc[o16][a] = fmaf(xq[a][3], wv.w, acc[o16][a]);
                    }
                }
            }
        }
    }

#pragma unroll
    for (int o16 = 0; o16 < 16; ++o16) {
        const int o = ogg * 16 + o16;
        const float bv = bias[o];
#pragma unroll
        for (int a = 0; a < NA; ++a) {
            float r = acc[o16][a] + bv;
            if (ACT) r = lrelu(r);
            y[((size_t)b * COUT + o) * LOUT + t0 + lane + 64 * a] = r;
        }
    }
}

// ---------------------------------------------------------------------------
// h5qin_fused (r10-proven): h5 (256->64,K=1) + q_in (64->64,K=1), one kernel.
// ---------------------------------------------------------------------------
__global__ __launch_bounds__(256) void h5qin_fused(const float* __restrict__ x,
                                                   const float* __restrict__ wq5,
                                                   const float* __restrict__ b5,
                                                   const float* __restrict__ wqq,
                                                   const float* __restrict__ qb,
                                                   float* __restrict__ qin)
{
    constexpr int RS = 20;
    __shared__ float xsT[128][RS];
    __shared__ float mid[4][128][RS];

    const int tid  = threadIdx.x;
    const int lane = tid & 63;
    const int wid  = __builtin_amdgcn_readfirstlane(tid >> 6);
    const int t0   = blockIdx.x * 128;
    const int b    = blockIdx.z;

    const float* xb = x + (size_t)b * 256 * 1024;

    float acc[16][2];
#pragma unroll
    for (int o16 = 0; o16 < 16; ++o16) { acc[o16][0] = 0.f; acc[o16][1] = 0.f; }

    for (int cb = 0; cb < 16; ++cb) {
        if (cb) __syncthreads();
        for (int idx = tid; idx < 16 * 128; idx += 256) {
            int i = idx >> 7, s = idx & 127;
            int g = t0 + s;
            float v = (g >= 0 && g < 1024) ? xb[(size_t)(cb * 16 + i) * 1024 + g] : 0.f;
            int c = (((i >> 2) ^ ((s >> 3) & 3)) << 2) | (i & 3);
            xsT[s][c] = v;
        }
        __syncthreads();

#pragma unroll
        for (int iq = 0; iq < 4; ++iq) {
            float xq[2][4];
#pragma unroll
            for (int a = 0; a < 2; ++a) {
                int u = lane + 64 * a;
                int col = ((iq ^ ((u >> 3) & 3)) << 2);
                float4 t = *(const float4*)&xsT[u][col];
                xq[a][0] = t.x; xq[a][1] = t.y; xq[a][2] = t.z; xq[a][3] = t.w;
            }
            const float* wp = wq5 + (((size_t)cb * 4 + iq) * 4 + wid) * 64;
#pragma unroll
            for (int o16 = 0; o16 < 16; ++o16) {
                float4 wv = *(const float4*)&wp[o16 * 4];
#pragma unroll
                for (int a = 0; a < 2; ++a) {
                    acc[o16][a] = fmaf(xq[a][0], wv.x, acc[o16][a]);
                    acc[o16][a] = fmaf(xq[a][1], wv.y, acc[o16][a]);
                    acc[o16][a] = fmaf(xq[a][2], wv.z, acc[o16][a]);
                    acc[o16][a] = fmaf(xq[a][3], wv.w, acc[o16][a]);
                }
            }
        }
    }

    __syncthreads();
#pragma unroll
    for (int o16 = 0; o16 < 16; ++o16) {
        const int o = wid * 16 + o16;
        const float bv = b5[o];
#pragma unroll
        for (int a = 0; a < 2; ++a) {
            float r = lrelu(acc[o16][a] + bv);
            int u = lane + 64 * a;
            int c = (((o16 >> 2) ^ ((u >> 3) & 3)) << 2) | (o16 & 3);
            mid[wid][u][c] = r;
        }
    }
    __syncthreads();

    float acc2[16][2];
#pragma unroll
    for (int o16 = 0; o16 < 16; ++o16) { acc2[o16][0] = 0.f; acc2[o16][1] = 0.f; }

#pragma unroll
    for (int cb2 = 0; cb2 < 4; ++cb2) {
#pragma unroll
        for (int iq = 0; iq < 4; ++iq) {
            float xq[2][4];
#pragma unroll
            for (int a = 0; a < 2; ++a) {
                int u = lane + 64 * a;
                int col = ((iq ^ ((u >> 3) & 3)) << 2);
                float4 t = *(const float4*)&mid[cb2][u][col];
                xq[a][0] = t.x; xq[a][1] = t.y; xq[a][2] = t.z; xq[a][3] = t.w;
            }
            const float* wp = wqq + (((size_t)cb2 * 4 + iq) * 4 + wid) * 64;
#pragma unroll
            for (int o16 = 0; o16 < 16; ++o16) {
                float4 wv = *(const float4*)&wp[o16 * 4];
#pragma unroll
                for (int a = 0; a < 2; ++a) {
                    acc2[o16][a] = fmaf(xq[a][0], wv.x, acc2[o16][a]);
                    acc2[o16][a] = fmaf(xq[a][1], wv.y, acc2[o16][a]);
                    acc2[o16][a] = fmaf(xq[a][2], wv.z, acc2[o16][a]);
                    acc2[o16][a] = fmaf(xq[a][3], wv.w, acc2[o16][a]);
                }
            }
        }
    }

#pragma unroll
    for (int o16 = 0; o16 < 16; ++o16) {
        const int o = wid * 16 + o16;
        const float bv = qb[o];
#pragma unroll
        for (int a = 0; a < 2; ++a)
            qin[((size_t)b * 64 + o) * 1024 + t0 + lane + 64 * a] = acc2[o16][a] + bv;
    }
}

// ---------------------------------------------------------------------------
// E1 oneDNN order (bit-exact, frozen).
// ---------------------------------------------------------------------------
__global__ __launch_bounds__(256) void e1_dnn(const float* __restrict__ x,
                                              const float* __restrict__ w1,
                                              const float* __restrict__ b1,
                                              float* __restrict__ y)
{
    const int tid = threadIdx.x;
    const int t0  = blockIdx.x * 1024 + tid * 4;
    const int o   = blockIdx.y;
    const int b   = blockIdx.z;

    float wr[2][4];
#pragma unroll
    for (int i = 0; i < 2; ++i)
#pragma unroll
        for (int k = 0; k < 4; ++k) wr[i][k] = w1[(o * 2 + i) * 4 + k];
    const float bv = b1[o];

    float acc[4] = {0.f, 0.f, 0.f, 0.f};
#pragma unroll
    for (int k = 0; k < 4; ++k)
#pragma unroll
        for (int i = 0; i < 2; ++i) {
            const float* xb = x + ((size_t)b * 2 + i) * 8192;
#pragma unroll
            for (int a = 0; a < 4; ++a) {
                int p = (t0 + a) * 2 - 1 + k;
                float v = (p >= 0 && p < 8192) ? xb[p] : 0.f;
                acc[a] = fmaf(v, wr[i][k], acc[a]);
            }
        }
    float4 r;
    r.x = lrelu(acc[0] + bv); r.y = lrelu(acc[1] + bv);
    r.z = lrelu(acc[2] + bv); r.w = lrelu(acc[3] + bv);
    *(float4*)&y[((size_t)b * 128 + o) * 4096 + t0] = r;
}

// ---------------------------------------------------------------------------
// Codebook prep + VQ (vq_exact2: r8-r12-proven).
// ---------------------------------------------------------------------------
__global__ void cbt_kernel(const float* __restrict__ cb, float* __restrict__ cbT)
{
    int idx = blockIdx.x * 256 + threadIdx.x;
    if (idx < 512 * 64) {
        int k = idx >> 6, d = idx & 63;
        cbT[d * 512 + k] = cb[idx];
    }
}

__global__ void norms_kernel(const float* __restrict__ cb, float* __restrict__ norms)
{
#pragma clang fp contract(off)
    int k = blockIdx.x * 256 + threadIdx.x;
    if (k < 512) {
        float s = 0.f;
        for (int d = 0; d < 64; ++d) {
            float c = cb[k * 64 + d];
            float sq = c * c;
            s = s + sq;
        }
        norms[k] = s;
    }
}

__global__ __launch_bounds__(256) void vq_exact2(const float* __restrict__ qin,
                                                 const float* __restrict__ cb,
                                                 const float* __restrict__ cbT,
                                                 const float* __restrict__ norms,
                                                 float* __restrict__ st,
                                                 double* __restrict__ lacc)
{
#pragma clang fp contract(off)
    __shared__ double wsum[8];
    const int tid  = threadIdx.x;
    const int lane = tid & 63;
    const int wv   = tid >> 6;
    const size_t n0 = (size_t)blockIdx.x * 8 + wv * 2;

    const float qv0 = qin[n0 * 64 + lane];
    const float qv1 = qin[(n0 + 1) * 64 + lane];

    float A0 = 0.f, A1 = 0.f;
    for (int d = 0; d < 64; ++d) {
        float q0 = __shfl(qv0, d);
        float s0 = q0 * q0;
        A0 = A0 + s0;
        float q1 = __shfl(qv1, d);
        float s1 = q1 * q1;
        A1 = A1 + s1;
    }

    float AB0[8] = {0.f,0.f,0.f,0.f,0.f,0.f,0.f,0.f};
    float AB1[8] = {0.f,0.f,0.f,0.f,0.f,0.f,0.f,0.f};
    for (int d = 0; d < 64; ++d) {
        float q0 = __shfl(qv0, d);
        float q1 = __shfl(qv1, d);
#pragma unroll
        for (int r = 0; r < 8; ++r) {
            float c = cbT[d * 512 + r * 64 + lane];
            AB0[r] = fmaf(q0, c, AB0[r]);
            AB1[r] = fmaf(q1, c, AB1[r]);
        }
    }

    double parts[2];
#pragma unroll
    for (int j = 0; j < 2; ++j) {
        const float qv = j ? qv1 : qv0;
        const float A  = j ? A1 : A0;
        const float* AB = j ? AB1 : AB0;
        const size_t n = n0 + j;

        float bd = 1e30f;
        int   bk = 0x7fffffff;
#pragma unroll
        for (int r = 0; r < 8; ++r) {
            int k = r * 64 + lane;
            float t1 = A + norms[k];
            float c2 = 2.f * AB[r];
            float dk = t1 - c2;
            if (dk < bd) { bd = dk; bk = k; }
        }
#pragma unroll
        for (int off = 32; off > 0; off >>= 1) {
            float od = __shfl_down(bd, off);
            int   ok = __shfl_down(bk, off);
            if (od < bd || (od == bd && ok < bk)) { bd = od; bk = ok; }
        }
        const int kb = __shfl(bk, 0);

        const float c   = cb[(size_t)kb * 64 + lane];
        const float dif = c - qv;
        const float stv = qv + dif;
        st[n * 64 + lane] = stv;
        float sq = dif * dif;
        double part = (double)sq;
#pragma unroll
        for (int off = 32; off > 0; off >>= 1) part += __shfl_down(part, off);
        parts[j] = part;
    }
    if (lane == 0) { wsum[wv * 2] = parts[0]; wsum[wv * 2 + 1] = parts[1]; }
    __syncthreads();
    if (tid == 0)
        atomicAdd(lacc, ((wsum[0] + wsum[1]) + (wsum[2] + wsum[3]))
                      + ((wsum[4] + wsum[5]) + (wsum[6] + wsum[7])));
}

__global__ void zero_kernel(double* __restrict__ p) { p[0] = 0.0; }

__global__ void finalize_kernel(const double* __restrict__ acc, float* __restrict__ out)
{
    out[0] = (float)(1.25 * (acc[0] / 4194304.0));
}

// ---------------------------------------------------------------------------
// fp32 conv (decoder g1). OSPLIT=true: epilogue emits bf16 hi/lo [B][L][C].
// ---------------------------------------------------------------------------
template<int CIN, int COUT, int K, int STRIDE, int PAD, bool ACT, int LIN, int LOUT, int CI_CHUNK, int WT, bool OSPLIT>
__global__ __launch_bounds__(256) void conv_kernel(const float* __restrict__ x,
                                                   const float* __restrict__ w,
                                                   const float* __restrict__ bias,
                                                   float* __restrict__ y,
                                                   u16* __restrict__ yhi,
                                                   u16* __restrict__ ylo)
{
    constexpr int SPAN  = 127 * STRIDE + K;
    constexpr int SPANP = ((SPAN + 11) & ~3);
    constexpr int NEED  = 3 * STRIDE + K;
    constexpr int NV    = (NEED + 3) / 4;
    constexpr int KP    = (K >= 3) ? 4 : K;

    __shared__ float xs[CI_CHUNK][SPANP];
    __shared__ float ws[32][CI_CHUNK][KP];

    const int tid = threadIdx.x;
    const int tt  = tid & 31;
    const int tg  = tid >> 5;
    const int t0  = blockIdx.x * 128;
    const int ob  = blockIdx.y * 32;
    const int b   = blockIdx.z;

    float acc[4][4];
#pragma unroll
    for (int j = 0; j < 4; ++j) { acc[j][0]=0.f; acc[j][1]=0.f; acc[j][2]=0.f; acc[j][3]=0.f; }

    const float* xb = x + (size_t)b * CIN * LIN;
    const int x0 = t0 * STRIDE - PAD;

    for (int ci = 0; ci < CIN; ci += CI_CHUNK) {
        for (int idx = tid; idx < CI_CHUNK * SPAN; idx += 256) {
            int i = idx / SPAN, s = idx - i * SPAN;
            int tin = x0 + s;
            xs[i][s] = (tin >= 0 && tin < LIN) ? xb[(size_t)(ci + i) * LIN + tin] : 0.f;
        }
        for (int idx = tid; idx < 32 * CI_CHUNK * K; idx += 256) {
            int o = idx / (CI_CHUNK * K);
            int rem = idx - o * (CI_CHUNK * K);
            int i = rem / K, k = rem - i * K;
            if constexpr (WT == 0)
                ws[o][i][k] = w[((size_t)(ob + o) * CIN + (ci + i)) * K + k];
            else
                ws[o][i][k] = w[((size_t)(ci + i) * COUT + (ob + o)) * K + (K - 1 - k)];
        }
        __syncthreads();

#pragma unroll 4
        for (int i = 0; i < CI_CHUNK; ++i) {
            float xv[NV * 4];
#pragma unroll
            for (int v = 0; v < NV; ++v) {
                float4 t = *(const float4*)&xs[i][tt * 4 * STRIDE + 4 * v];
                xv[4*v+0]=t.x; xv[4*v+1]=t.y; xv[4*v+2]=t.z; xv[4*v+3]=t.w;
            }
#pragma unroll
            for (int j = 0; j < 4; ++j) {
                float wv[KP];
                if constexpr (KP == 4) {
                    float4 t = *(const float4*)&ws[tg*4+j][i][0];
                    wv[0]=t.x; wv[1]=t.y; wv[2]=t.z; wv[3]=t.w;
                } else {
                    wv[0] = ws[tg*4+j][i][0];
                    if constexpr (KP >= 2) wv[1] = ws[tg*4+j][i][1];
                }
#pragma unroll
                for (int a = 0; a < 4; ++a)
#pragma unroll
                    for (int k = 0; k < K; ++k)
                        acc[j][a] += xv[a * STRIDE + k] * wv[k];
            }
        }
        __syncthreads();
    }

    if constexpr (OSPLIT) {
        float rv[4][4];
#pragma unroll
        for (int j = 0; j < 4; ++j) {
            const float bv = bias[ob + tg * 4 + j];
#pragma unroll
            for (int a = 0; a < 4; ++a) {
                float r = acc[j][a] + bv;
                rv[j][a] = ACT ? lrelu(r) : r;
            }
        }
#pragma unroll
        for (int a = 0; a < 4; ++a) {
            u16x4 hv, lv;
#pragma unroll
            for (int j = 0; j < 4; ++j) {
                u16 h = f2bf(rv[j][a]);
                hv[j] = h;
                lv[j] = f2bf(rv[j][a] - bfhi(h));
            }
            const int t = t0 + 4 * tt + a;
            size_t oa = ((size_t)b * LOUT + t) * COUT + ob + tg * 4;
            *(u16x4*)&yhi[oa] = hv;
            *(u16x4*)&ylo[oa] = lv;
        }
    } else {
#pragma unroll
        for (int j = 0; j < 4; ++j) {
            const int o = ob + tg * 4 + j;
            const float bv = bias[o];
            float4 r;
            r.x = acc[j][0] + bv; r.y = acc[j][1] + bv; r.z = acc[j][2] + bv; r.w = acc[j][3] + bv;
            if constexpr (ACT) { r.x=lrelu(r.x); r.y=lrelu(r.y); r.z=lrelu(r.z); r.w=lrelu(r.w); }
            *(float4*)&y[((size_t)b * COUT + o) * LOUT + t0 + 4 * tt] = r;
        }
    }
}

// ---------------------------------------------------------------------------
// Repack ConvT1d weights [CIN][COUT][4] into per-lane MFMA A-fragments (hi/lo).
// ---------------------------------------------------------------------------
template<int CIN, int COUT>
__global__ __launch_bounds__(256) void repack_wt_mfma(const float* __restrict__ w,
                                                      u16* __restrict__ wf)
{
    constexpr int NKC = CIN / 32, NOG = COUT / 16;
    int idx = blockIdx.x * 256 + threadIdx.x;
    if (idx >= NKC * NOG * 4 * 2 * 512) return;
    int e    = idx & 7;
    int lane = (idx >> 3) & 63;
    int h    = (idx >> 9) & 1;
    int pt   = (idx >> 10) & 3;
    int rest = idx >> 12;
    int og = rest & (NOG - 1);
    int kc = rest / NOG;
    int i = kc * 32 + (lane >> 4) * 8 + e;
    int o = og * 16 + (lane & 15);
    int k = (pt == 0) ? 1 : (pt == 1) ? 3 : (pt == 2) ? 0 : 2;
    float f = w[((size_t)i * COUT + o) * 4 + k];
    u16 hb = f2bf(f);
    u16 v  = h ? f2bf(f - bfhi(hb)) : hb;
    wf[idx] = v;
}

// ---------------------------------------------------------------------------
// Repack conv-like weights -> double-split MFMA fragments (decoder g2).
// ---------------------------------------------------------------------------
template<int CIN, int COUT, int K, int WT>
__global__ __launch_bounds__(256) void repack_wc_mfma(const float* __restrict__ w,
                                                      u16* __restrict__ wf)
{
    constexpr int NKC = CIN / 32, NOG = COUT / 16;
    int idx = blockIdx.x * 256 + threadIdx.x;
    if (idx >= NKC * NOG * K * 2 * 512) return;
    int e    = idx & 7;
    int lane = (idx >> 3) & 63;
    int h    = (idx >> 9) & 1;
    int rem  = idx >> 10;
    int kt   = rem % K;
    int rest = rem / K;
    int og = rest % NOG;
    int kc = rest / NOG;
    int i = kc * 32 + (lane >> 4) * 8 + e;
    int o = og * 16 + (lane & 15);
    float f;
    if constexpr (WT == 0)
        f = w[((size_t)o * CIN + i) * K + kt];
    else
        f = w[((size_t)i * COUT + o) * K + (K - 1 - kt)];
    u16 hb = f2bf(f);
    u16 v  = h ? f2bf(f - bfhi(hb)) : hb;
    wf[idx] = v;
}

#define MFMA_B16(a,b,c) __builtin_amdgcn_mfma_f32_16x16x32_bf16((a),(b),(c),0,0,0)
#define LDSB(arr,row,slot) (*(const bf16x8*)&(arr)[(((row)*16 + ((slot) ^ ((row)&7)))*8)])

// ---------------------------------------------------------------------------
// MFMA Conv1d K=3 S=1 P=1 via double split-bf16 (decoder g2). (256,2) = the
// r3-proven codegen; r12's (256,4) hint measured null.
// ---------------------------------------------------------------------------
template<int CIN, int COUT, int LIN>
__global__ __launch_bounds__(256, 2) void conv3_mfma(const u16* __restrict__ xhi,
                                                     const u16* __restrict__ xlo,
                                                     const u16* __restrict__ wf,
                                                     const float* __restrict__ bias,
                                                     u16* __restrict__ yhi,
                                                     u16* __restrict__ ylo)
{
    constexpr int NOG = COUT / 16;

    __shared__ __attribute__((aligned(16))) u16 lhi[66 * 128];
    __shared__ __attribute__((aligned(16))) u16 llo[66 * 128];

    const int tid  = threadIdx.x;
    const int lane = tid & 63;
    const int wid  = tid >> 6;
    const int n    = lane & 15;
    const int g    = lane >> 4;
    const int u0   = blockIdx.x * 64;
    const int ogp  = blockIdx.y * 4 + wid;
    const int og0  = ogp * 2;
    const int b    = blockIdx.z;

    f32x4 acc[2][4];
#pragma unroll
    for (int og = 0; og < 2; ++og)
#pragma unroll
        for (int us = 0; us < 4; ++us) {
            f32x4 z = {0.f, 0.f, 0.f, 0.f};
            acc[og][us] = z;
        }

    for (int ch = 0; ch < CIN; ch += 128) {
        if (ch) __syncthreads();
        for (int idx = tid; idx < 1056; idx += 256) {
            int row = idx >> 4, slot = idx & 15;
            int u = u0 - 1 + row;
            uint4 vh = {0u,0u,0u,0u}, vl = {0u,0u,0u,0u};
            if (u >= 0 && u < LIN) {
                size_t ga = ((size_t)b * LIN + u) * CIN + ch + slot * 8;
                vh = *(const uint4*)&xhi[ga];
                vl = *(const uint4*)&xlo[ga];
            }
            int sl = slot ^ (row & 7);
            *(uint4*)&lhi[(row * 16 + sl) * 8] = vh;
            *(uint4*)&llo[(row * 16 + sl) * 8] = vl;
        }
        __syncthreads();

#pragma unroll
        for (int kc = 0; kc < 4; ++kc) {
            const int kcg = (ch >> 5) + kc;
            const u16* wb = wf + ((size_t)(kcg * NOG + og0) * 3) * 1024 + lane * 8;
            bf16x8 A[2][3][2];
#pragma unroll
            for (int og = 0; og < 2; ++og)
#pragma unroll
                for (int kt = 0; kt < 3; ++kt)
#pragma unroll
                    for (int h = 0; h < 2; ++h)
                        A[og][kt][h] = *(const bf16x8*)(wb + (size_t)((og * 3 + kt) * 2 + h) * 512);

            const int slot = kc * 4 + g;
#pragma unroll
            for (int us = 0; us < 4; ++us) {
                const int r0 = us * 16 + n;
                bf16x8 Bh[3], Bl[3];
#pragma unroll
                for (int k = 0; k < 3; ++k) {
                    Bh[k] = LDSB(lhi, r0 + k, slot);
                    Bl[k] = LDSB(llo, r0 + k, slot);
                }
#pragma unroll
                for (int og = 0; og < 2; ++og) {
                    f32x4 a = acc[og][us];
#pragma unroll
                    for (int k = 0; k < 3; ++k) {
                        a = MFMA_B16(A[og][k][0], Bh[k], a);
                        a = MFMA_B16(A[og][k][0], Bl[k], a);
                        a = MFMA_B16(A[og][k][1], Bh[k], a);
                    }
                    acc[og][us] = a;
                }
            }
        }
    }

#pragma unroll
    for (int og = 0; og < 2; ++og) {
        const int ob = (og0 + og) * 16 + g * 4;
        const float4 bq = *(const float4*)&bias[ob];
        const float bvr[4] = {bq.x, bq.y, bq.z, bq.w};
#pragma unroll
        for (int us = 0; us < 4; ++us) {
            const int t = u0 + us * 16 + n;
            u16x4 hv, lv;
#pragma unroll
            for (int r = 0; r < 4; ++r) {
                float v = lrelu(acc[og][us][r] + bvr[r]);
                u16 h = f2bf(v);
                hv[r] = h;
                lv[r] = f2bf(v - bfhi(h));
            }
            size_t oa = ((size_t)b * LIN + t) * COUT + ob;
            *(u16x4*)&yhi[oa] = hv;
            *(u16x4*)&ylo[oa] = lv;
        }
    }
}

// ---------------------------------------------------------------------------
// MFMA ConvTranspose1d (K=4, S=2, P=1) via double split-bf16 (decoder g3/g4).
// ---------------------------------------------------------------------------
template<int CIN, int COUT, int LIN, bool OSPLIT>
__global__ __launch_bounds__(256, 2) void convt_mfma(const u16* __restrict__ xhi,
                                                     const u16* __restrict__ xlo,
                                                     const u16* __restrict__ wf,
                                                     const float* __restrict__ bias,
                                                     float* __restrict__ y,
                                                     u16* __restrict__ yhi,
                                                     u16* __restrict__ ylo)
{
    constexpr int LOUT = 2 * LIN;
    constexpr int NOG  = COUT / 16;

    __shared__ __attribute__((aligned(16))) u16 lhi[66 * 128];
    __shared__ __attribute__((aligned(16))) u16 llo[66 * 128];

    const int tid  = threadIdx.x;
    const int lane = tid & 63;
    const int wid  = tid >> 6;
    const int n    = lane & 15;
    const int g    = lane >> 4;
    const int u0   = blockIdx.x * 64;
    const int ogp  = blockIdx.y * 4 + wid;
    const int og0  = ogp * 2;
    const int b    = blockIdx.z;

    f32x4 acc[2][4][2];
#pragma unroll
    for (int og = 0; og < 2; ++og)
#pragma unroll
        for (int us = 0; us < 4; ++us)
#pragma unroll
            for (int p = 0; p < 2; ++p) {
                f32x4 z = {0.f, 0.f, 0.f, 0.f};
                acc[og][us][p] = z;
            }

    for (int ch = 0; ch < CIN; ch += 128) {
        if (ch) __syncthreads();
        for (int idx = tid; idx < 1056; idx += 256) {
            int row = idx >> 4, slot = idx & 15;
            int u = u0 - 1 + row;
            uint4 vh = {0u,0u,0u,0u}, vl = {0u,0u,0u,0u};
            if (u >= 0 && u < LIN) {
                size_t ga = ((size_t)b * LIN + u) * CIN + ch + slot * 8;
                vh = *(const uint4*)&xhi[ga];
                vl = *(const uint4*)&xlo[ga];
            }
            int sl = slot ^ (row & 7);
            *(uint4*)&lhi[(row * 16 + sl) * 8] = vh;
            *(uint4*)&llo[(row * 16 + sl) * 8] = vl;
        }
        __syncthreads();

#pragma unroll
        for (int kc = 0; kc < 4; ++kc) {
            const int kcg = (ch >> 5) + kc;
            const u16* w0 = wf + ((size_t)kcg * NOG + og0) * 4096 + lane * 8;
            bf16x8 A[2][8];
#pragma unroll
            for (int q = 0; q < 8; ++q) A[0][q] = *(const bf16x8*)(w0 + q * 512);
#pragma unroll
            for (int q = 0; q < 8; ++q) A[1][q] = *(const bf16x8*)(w0 + (8 + q) * 512);

            const int slot = kc * 4 + g;
#pragma unroll
            for (int us = 0; us < 4; ++us) {
                const int r0 = us * 16 + n;
                bf16x8 Bm1h = LDSB(lhi, r0,     slot);
                bf16x8 Bm1l = LDSB(llo, r0,     slot);
                bf16x8 B0h  = LDSB(lhi, r0 + 1, slot);
                bf16x8 B0l  = LDSB(llo, r0 + 1, slot);
                bf16x8 Bp1h = LDSB(lhi, r0 + 2, slot);
                bf16x8 Bp1l = LDSB(llo, r0 + 2, slot);
#pragma unroll
                for (int og = 0; og < 2; ++og) {
                    f32x4 ae = acc[og][us][0];
                    f32x4 ao = acc[og][us][1];
                    ae = MFMA_B16(A[og][0], B0h,  ae);
                    ae = MFMA_B16(A[og][0], B0l,  ae);
                    ae = MFMA_B16(A[og][1], B0h,  ae);
                    ae = MFMA_B16(A[og][2], Bm1h, ae);
                    ae = MFMA_B16(A[og][2], Bm1l, ae);
                    ae = MFMA_B16(A[og][3], Bm1h, ae);
                    ao = MFMA_B16(A[og][4], Bp1h, ao);
                    ao = MFMA_B16(A[og][4], Bp1l, ao);
                    ao = MFMA_B16(A[og][5], Bp1h, ao);
                    ao = MFMA_B16(A[og][6], B0h,  ao);
                    ao = MFMA_B16(A[og][6], B0l,  ao);
                    ao = MFMA_B16(A[og][7], B0h,  ao);
                    acc[og][us][0] = ae;
                    acc[og][us][1] = ao;
                }
            }
        }
    }

#pragma unroll
    for (int og = 0; og < 2; ++og) {
        const int ob = (og0 + og) * 16 + g * 4;
        const float4 bq = *(const float4*)&bias[ob];
        const float bvr[4] = {bq.x, bq.y, bq.z, bq.w};
#pragma unroll
        for (int us = 0; us < 4; ++us) {
            const int U = u0 + us * 16 + n;
            if constexpr (OSPLIT) {
                u16x4 he, le, ho, lo_;
#pragma unroll
                for (int r = 0; r < 4; ++r) {
                    float ev = lrelu(acc[og][us][0][r] + bvr[r]);
                    float ov = lrelu(acc[og][us][1][r] + bvr[r]);
                    u16 hev = f2bf(ev); he[r] = hev; le[r]  = f2bf(ev - bfhi(hev));
                    u16 hov = f2bf(ov); ho[r] = hov; lo_[r] = f2bf(ov - bfhi(hov));
                }
                size_t oe = ((size_t)b * LOUT + 2 * U) * COUT + ob;
                size_t oo = ((size_t)b * LOUT + 2 * U + 1) * COUT + ob;
                *(u16x4*)&yhi[oe] = he;
                *(u16x4*)&ylo[oe] = le;
                *(u16x4*)&yhi[oo] = ho;
                *(u16x4*)&ylo[oo] = lo_;
            } else {
#pragma unroll
                for (int r = 0; r < 4; ++r) {
                    float ev = acc[og][us][0][r] + bvr[r];
                    float ov = acc[og][us][1][r] + bvr[r];
                    float2 f2;
                    f2.x = lrelu(ev);
                    f2.y = lrelu(ov);
                    *(float2*)&y[((size_t)b * COUT + ob + r) * LOUT + 2 * U] = f2;
                }
            }
        }
    }
}

// ---------------------------------------------------------------------------
// d5b (r8-r12-proven): final convT 128->2, 128-thread blocks, u-tile 128.
// ---------------------------------------------------------------------------
__global__ __launch_bounds__(128) void d5b_kernel(const float* __restrict__ x,
                                                  const float* __restrict__ w,
                                                  const float* __restrict__ bias,
                                                  float* __restrict__ y)
{
    constexpr int CIN = 128, LIN = 4096, LOUT = 8192, CI_CHUNK = 16;
    constexpr int SPAN = 131, SPANP = 136;
    __shared__ float xs[CI_CHUNK][SPANP];
    __shared__ float wsm[2][CIN][4];
    __shared__ float bsm[2];

    const int tid = threadIdx.x;
    const int mb  = blockIdx.x * 128;
    const int b   = blockIdx.y;

    for (int idx = tid; idx < 1024; idx += 128) {
        int k = idx & 3, t = idx >> 2;
        int i = t & 127, o = t >> 7;
        wsm[o][i][k] = w[((size_t)i * 2 + o) * 4 + k];
    }
    if (tid < 2) bsm[tid] = bias[tid];

    float acc[2][2] = {{0.f, 0.f}, {0.f, 0.f}};
    const float* xb = x + (size_t)b * CIN * LIN;

    for (int ci = 0; ci < CIN; ci += CI_CHUNK) {
        for (int idx = tid; idx < CI_CHUNK * SPAN; idx += 128) {
            int i = idx / SPAN, s = idx - i * SPAN;
            int m = mb - 1 + s;
            xs[i][s] = (m >= 0 && m < LIN) ? xb[(size_t)(ci + i) * LIN + m] : 0.f;
        }
        __syncthreads();
#pragma unroll 4
        for (int i = 0; i < CI_CHUNK; ++i) {
            float a0 = xs[i][tid];
            float a1 = xs[i][tid + 1];
            float a2 = xs[i][tid + 2];
#pragma unroll
            for (int o = 0; o < 2; ++o) {
                float4 wv = *(const float4*)&wsm[o][ci + i][0];
                acc[o][0] += a1 * wv.y + a0 * wv.w;
                acc[o][1] += a2 * wv.x + a1 * wv.z;
            }
        }
        __syncthreads();
    }

    const int u = mb + tid;
#pragma unroll
    for (int o = 0; o < 2; ++o) {
        float2 r;
        r.x = acc[o][0] + bsm[o];
        r.y = acc[o][1] + bsm[o];
        *(float2*)&y[((size_t)b * 2 + o) * LOUT + 2 * u] = r;
    }
}

// ---------------------------------------------------------------------------
// Workspace layout = round 3 (proven):
//   A 0 | Bb 16777216 | C 33554432 | cbT 41943040 | norms 41975808
//   lacc 41976320 | wq2 41976336 | wq3 42107408 | wq4 42369552
//   wq5 42566160 | wqq 42582544 | wf3 42586640 | wf4 42848784 | wf2 42979856
// ---------------------------------------------------------------------------
extern "C" void kernel_launch(void* const* d_in, const int* in_sizes, int n_in,
                              void* d_out, int out_size, void* d_ws, size_t ws_size,
                              hipStream_t stream)
{
    const float* x   = (const float*)d_in[0];
    const float* w1  = (const float*)d_in[1];  const float* b1  = (const float*)d_in[2];
    const float* w2  = (const float*)d_in[3];  const float* b2  = (const float*)d_in[4];
    const float* w3  = (const float*)d_in[5];  const float* b3  = (const float*)d_in[6];
    const float* w4  = (const float*)d_in[7];  const float* b4  = (const float*)d_in[8];
    const float* w5  = (const float*)d_in[9];  const float* b5  = (const float*)d_in[10];
    const float* qw  = (const float*)d_in[11]; const float* qb  = (const float*)d_in[12];
    const float* cbk = (const float*)d_in[13];
    const float* dw1 = (const float*)d_in[14]; const float* db1 = (const float*)d_in[15];
    const float* dw2 = (const float*)d_in[16]; const float* db2 = (const float*)d_in[17];
    const float* dw3 = (const float*)d_in[18]; const float* db3 = (const float*)d_in[19];
    const float* dw4 = (const float*)d_in[20]; const float* db4 = (const float*)d_in[21];
    const float* dw5 = (const float*)d_in[22]; const float* db5 = (const float*)d_in[23];

    float* wsf   = (float*)d_ws;
    float* A     = wsf;
    float* Bb    = wsf + 16777216;
    float* C     = wsf + 33554432;
    float* cbT   = wsf + 41943040;
    float* norms = wsf + 41975808;
    double* lacc = (double*)(wsf + 41976320);
    float* wq2   = wsf + 41976336;
    float* wq3   = wsf + 42107408;
    float* wq4   = wsf + 42369552;
    float* wq5   = wsf + 42566160;
    float* wqq   = wsf + 42582544;
    u16*   wf3   = (u16*)(wsf + 42586640);
    u16*   wf4   = (u16*)(wsf + 42848784);
    u16*   wf2   = (u16*)(wsf + 42979856);

    float* h4  = A;
    float* qin = A + 10485760;
    float* st  = A + 12582912;

    cbt_kernel<<<128, 256, 0, stream>>>(cbk, cbT);
    norms_kernel<<<2, 256, 0, stream>>>(cbk, norms);
    zero_kernel<<<1, 1, 0, stream>>>(lacc);
    repack_w<128, 256, 4><<<512, 256, 0, stream>>>(w2, wq2);
    repack_w<256, 256, 4><<<1024, 256, 0, stream>>>(w3, wq3);
    repack_w<256, 256, 3><<<768, 256, 0, stream>>>(w4, wq4);
    repack_w<256, 64, 1><<<64, 256, 0, stream>>>(w5, wq5);
    repack_w<64, 64, 1><<<16, 256, 0, stream>>>(qw, wqq);
    repack_wc_mfma<256, 256, 3, 1><<<1536, 256, 0, stream>>>(dw2, wf2);
    repack_wt_mfma<256, 256><<<2048, 256, 0, stream>>>(dw3, wf3);
    repack_wt_mfma<256, 128><<<1024, 256, 0, stream>>>(dw4, wf4);

    constexpr int BS = 32;
    for (int s = 0; s < 2; ++s) {
        const float* xs   = x + (size_t)s * BS * 2 * 8192;
        float*       decs = (float*)d_out + (size_t)s * BS * 2 * 8192;

        // ---- encoder: bit-exact chains; dnn8 = dnn5 chain @ 8 waves/block ----
        e1_dnn<<<dim3(4, 128, BS), 256, 0, stream>>>(xs, w1, b1, A);                                // h1
        conv_dnn8<128,256,4,2,1,true,4096,2048><<<dim3(16,2,BS),512,0,stream>>>(A,  wq2, b2, Bb);   // h2
        conv_dnn8<256,256,4,2,1,true,2048,1024><<<dim3(8,2,BS),512,0,stream>>>(Bb, wq3, b3, C);     // h3
        conv_dnn8<256,256,3,1,1,true,1024,1024><<<dim3(8,2,BS),512,0,stream>>>(C,  wq4, b4, h4);    // h4
        h5qin_fused<<<dim3(8, 1, BS), 256, 0, stream>>>(h4, wq5, b5, wqq, qb, qin);                 // h5 + q_in

        // ---- fp32 VQ (vq_exact2, r8-proven) ----
        vq_exact2<<<4096, 256, 0, stream>>>(qin, cbk, cbT, norms, st, lacc);

        // ---- decoder: g1 fp32 (split epilogue), g2/g3/g4 MFMA chain ----
        conv_kernel<64,256,1,1,0,true,1024,1024,32,1,true><<<dim3(8,8,BS),256,0,stream>>>(
            st, dw1, db1, nullptr, (u16*)C, (u16*)(C + 4194304));                                   // g1 -> hi/lo

        conv3_mfma<256,256,1024><<<dim3(16,2,BS),256,0,stream>>>(
            (const u16*)C, (const u16*)(C + 4194304), wf2, db2,
            (u16*)Bb, (u16*)(Bb + 4194304));                                                        // g2

        convt_mfma<256,256,1024,true><<<dim3(16,2,BS),256,0,stream>>>(
            (const u16*)Bb, (const u16*)(Bb + 4194304), wf3, db3,
            nullptr, (u16*)A, (u16*)(A + 8388608));                                                 // g3

        convt_mfma<256,128,2048,false><<<dim3(32,1,BS),256,0,stream>>>(
            (const u16*)A, (const u16*)(A + 8388608), wf4, db4,
            Bb, nullptr, nullptr);                                                                  // g4

        d5b_kernel<<<dim3(32, BS), 128, 0, stream>>>(Bb, dw5, db5, decs);                           // dec
    }

    finalize_kernel<<<1, 1, 0, stream>>>(lacc, (float*)d_out + 1048576);
}